// Round 12
// baseline (383.630 us; speedup 1.0000x reference)
//
#include <hip/hip_runtime.h>
#include <hip/hip_bf16.h>
#include <math.h>
#include <stdint.h>

#define HEADS 4
#define CH 64          // channels per head
#define HC 256         // HEADS*CH
#define NEG 0.2f
#define EPSV 1e-16f
#define NEGBIG -3.0e38f

typedef __attribute__((ext_vector_type(8))) short short8;
typedef __attribute__((ext_vector_type(4))) float f32x4;
typedef _Float16 f16_t;
typedef __fp16 fp16x2 __attribute__((ext_vector_type(2)));   // builtin-compatible

__device__ __forceinline__ float lrelu(float x) { return x > 0.f ? x : NEG * x; }

__device__ __forceinline__ unsigned short f2bf(float f) {
  __hip_bfloat16 b = __float2bfloat16(f);   // RNE
  return *reinterpret_cast<unsigned short*>(&b);
}
__device__ __forceinline__ unsigned short f16b(float f) {
  return __builtin_bit_cast(unsigned short, (f16_t)f);
}
// acc += dot(packed f16 pair a, packed f16 pair h)
__device__ __forceinline__ float dot2acc(unsigned int a, unsigned int h, float acc) {
#if __has_builtin(__builtin_amdgcn_fdot2)
  return __builtin_amdgcn_fdot2(__builtin_bit_cast(fp16x2, a),
                                __builtin_bit_cast(fp16x2, h), acc, false);
#else
  fp16x2 av = __builtin_bit_cast(fp16x2, a);
  fp16x2 hv = __builtin_bit_cast(fp16x2, h);
  return acc + (float)av[0] * (float)hv[0] + (float)av[1] * (float)hv[1];
#endif
}

// ---------------- weight prep (all 3 layers in one launch) ----------------
__global__ __launch_bounds__(256) void wprep3_k(const float* __restrict__ W0,
                                                const float* __restrict__ W1,
                                                const float* __restrict__ W2,
                                                unsigned short* __restrict__ T0,
                                                unsigned short* __restrict__ T1,
                                                unsigned short* __restrict__ T2) {
  int i = blockIdx.x * 256 + threadIdx.x;
  if (i < 65536) {
    int k = i >> 8, n = i & 255;
    T0[n * 256 + k] = f2bf(W0[i]);
  } else if (i < 81920) {
    int j = i - 65536, k = j >> 8, n = j & 255;
    T1[n * 64 + k] = f2bf(W1[j]);
  } else if (i < 98304) {
    int j = i - 81920, k = j >> 8, n = j & 255;
    T2[n * 64 + k] = f2bf(W2[j]);
  }
}

// ---------------- fused MFMA GEMM + attention-dot epilogue ----------------
// Templated on K (full unroll) and input dtype. Whole 32xK A-panel staged to
// LDS with one barrier; MFMA loop is barrier-free (B direct from L2-hot Wt).
// As (stride 268) and Cs (stride 258) alias one LDS buffer.
#define AS_STR 268
#define CS_STR 258
template <int K, int AF32>
__global__ __launch_bounds__(256) void mfma_gat_k(const float* __restrict__ Af,
                                                  const unsigned short* __restrict__ Ab,
                                                  const unsigned short* __restrict__ Wt,
                                                  const float* __restrict__ att_s,
                                                  const float* __restrict__ att_d,
                                                  unsigned short* __restrict__ ht16,
                                                  float* __restrict__ a_src,
                                                  float* __restrict__ a_dst,
                                                  int M) {
  __shared__ unsigned short Sh[32 * AS_STR];   // As during K loop; Cs after

  int tid = threadIdx.x;
  int bm = blockIdx.x * 32;
  int w = tid >> 6, l = tid & 63;
  int lr = l & 15, lk = l >> 4;
  int row_s = tid >> 3, seg = tid & 7;
  bool rowok = (bm + row_s < M);

  // ---- stage whole A panel: 32 x K bf16, all loads in flight ----
  if (AF32) {
    #pragma unroll
    for (int kq = 0; kq < K; kq += 32) {
      float4 v = make_float4(0.f, 0.f, 0.f, 0.f);
      if (rowok)
        v = *reinterpret_cast<const float4*>(Af + (size_t)(bm + row_s) * K + kq + seg * 4);
      ushort4 u;
      u.x = f2bf(v.x); u.y = f2bf(v.y); u.z = f2bf(v.z); u.w = f2bf(v.w);
      *reinterpret_cast<ushort4*>(&Sh[row_s * AS_STR + kq + seg * 4]) = u;
    }
  } else {
    #pragma unroll
    for (int kq = 0; kq < K; kq += 32) {
      ushort4 u = make_ushort4(0, 0, 0, 0);
      if (rowok)
        u = *reinterpret_cast<const ushort4*>(Ab + (size_t)(bm + row_s) * K + kq + seg * 4);
      *reinterpret_cast<ushort4*>(&Sh[row_s * AS_STR + kq + seg * 4]) = u;
    }
  }
  __syncthreads();

  f32x4 acc[2][4];
  #pragma unroll
  for (int rt = 0; rt < 2; ++rt)
    #pragma unroll
    for (int ct = 0; ct < 4; ++ct) {
      f32x4 z = {0.f, 0.f, 0.f, 0.f};
      acc[rt][ct] = z;
    }

  const unsigned short* wp0 = Wt + (size_t)(w * 64 + lr) * K + lk * 8;

  #pragma unroll
  for (int k0 = 0; k0 < K; k0 += 32) {
    short8 bfr[4];
    #pragma unroll
    for (int ct = 0; ct < 4; ++ct)
      bfr[ct] = *reinterpret_cast<const short8*>(wp0 + (size_t)ct * 16 * K + k0);
    #pragma unroll
    for (int rt = 0; rt < 2; ++rt) {
      short8 af = *reinterpret_cast<const short8*>(&Sh[(rt * 16 + lr) * AS_STR + k0 + lk * 8]);
      #pragma unroll
      for (int ct = 0; ct < 4; ++ct)
        acc[rt][ct] = __builtin_amdgcn_mfma_f32_16x16x32_bf16(af, bfr[ct], acc[rt][ct], 0, 0, 0);
    }
  }
  __syncthreads();   // all As reads done; Sh becomes Cs

  #pragma unroll
  for (int rt = 0; rt < 2; ++rt)
    #pragma unroll
    for (int ct = 0; ct < 4; ++ct)
      #pragma unroll
      for (int r = 0; r < 4; ++r) {
        int row = rt * 16 + lk * 4 + r;
        int c = ct * 16 + lr;
        Sh[row * CS_STR + c * 4 + w] = f16b(acc[rt][ct][r]);
      }
  __syncthreads();

  if (rowok) {
    ushort4* dst = reinterpret_cast<ushort4*>(ht16 + (size_t)(bm + row_s) * HC + seg * 32);
    const unsigned short* srcp = &Sh[row_s * CS_STR + seg * 32];
    #pragma unroll
    for (int q = 0; q < 4; ++q)
      dst[q] = *reinterpret_cast<const ushort4*>(srcp + q * 4);
  }

  {
    int nd = tid >> 3, q = tid & 7, h = q >> 1, half = q & 1;
    float ps = 0.f, pd = 0.f;
    const float* ats = att_s + h * 64 + half * 32;
    const float* atd = att_d + h * 64 + half * 32;
    const unsigned short* cp = &Sh[nd * CS_STR + (half * 32) * 4 + h];
    #pragma unroll
    for (int c = 0; c < 32; ++c) {
      float hv = (float)__builtin_bit_cast(f16_t, cp[c * 4]);
      ps += hv * ats[c];
      pd += hv * atd[c];
    }
    ps += __shfl_xor(ps, 1);
    pd += __shfl_xor(pd, 1);
    if (!(q & 1) && bm + nd < M) {
      a_src[(size_t)(bm + nd) * 4 + h] = ps;
      a_dst[(size_t)(bm + nd) * 4 + h] = pd;
    }
  }
}

// ================= CSR build (once per call) =================
__global__ __launch_bounds__(256) void hist_k(const int* __restrict__ dst, int* __restrict__ count, int E) {
  int e = blockIdx.x * blockDim.x + threadIdx.x;
  if (e < E) atomicAdd(&count[dst[e]], 1);
}

__global__ __launch_bounds__(512) void scan1_k(const int* __restrict__ count,
                                               int* __restrict__ rp,
                                               int* __restrict__ bsum, int n) {
  __shared__ int sh[512];
  int tx = threadIdx.x;
  int i = blockIdx.x * 512 + tx;
  int v = (i < n) ? count[i] : 0;
  sh[tx] = v;
  __syncthreads();
  #pragma unroll
  for (int off = 1; off < 512; off <<= 1) {
    int t = (tx >= off) ? sh[tx - off] : 0;
    __syncthreads();
    sh[tx] += t;
    __syncthreads();
  }
  if (i < n) rp[i] = sh[tx] - v;          // exclusive
  if (tx == 511) bsum[blockIdx.x] = sh[511];
}

__global__ __launch_bounds__(128) void scan2_k(int* __restrict__ bsum, int nb) {
  __shared__ int sh[128];
  int tx = threadIdx.x;
  int v = (tx < nb) ? bsum[tx] : 0;
  sh[tx] = v;
  __syncthreads();
  #pragma unroll
  for (int off = 1; off < 128; off <<= 1) {
    int t = (tx >= off) ? sh[tx - off] : 0;
    __syncthreads();
    sh[tx] += t;
    __syncthreads();
  }
  if (tx < nb) bsum[tx] = sh[tx] - v;      // exclusive
}

__global__ __launch_bounds__(512) void scan3_k(int* __restrict__ rp, const int* __restrict__ bsum,
                                               int n, int E) {
  int i = blockIdx.x * 512 + threadIdx.x;
  if (i < n) rp[i] += bsum[blockIdx.x];
  if (i == 0) rp[n] = E;
}

__global__ __launch_bounds__(256) void scatter_k(const int* __restrict__ src, const int* __restrict__ dst,
                                                 const int* __restrict__ rp, int* __restrict__ cursor,
                                                 int* __restrict__ csr_src, int E) {
  int e = blockIdx.x * blockDim.x + threadIdx.x;
  if (e >= E) return;
  int d = dst[e];
  int pos = rp[d] + atomicAdd(&cursor[d], 1);
  csr_src[pos] = src[e];
}

// ------------- FUSED segment softmax + gather-aggregate + finalize -------------
__global__ __launch_bounds__(256) void soft_agg_k(const int* __restrict__ rp,
                                                  const int* __restrict__ csr_src,
                                                  const float* __restrict__ a_src,
                                                  const float* __restrict__ a_dst,
                                                  const unsigned short* __restrict__ ht16,
                                                  const float* __restrict__ bias,
                                                  float* __restrict__ outf,
                                                  unsigned short* __restrict__ outb,
                                                  int N, int do_lsm) {
  __shared__ uint4 rec[4][17];              // 16 edge records + self record per wave
  int tid  = threadIdx.x;
  int w    = tid >> 6;
  int lane = tid & 63;
  int wid  = (blockIdx.x * blockDim.x + tid) >> 6;
  if (wid >= N) return;
  int rs = rp[wid], re = rp[wid + 1];
  int ep = lane & 15;          // edge slot in chunk
  int h  = lane >> 4;          // head

  float adh = a_dst[(size_t)wid * 4 + h];
  float ash = a_src[(size_t)wid * 4 + h];
  float es  = lrelu(ash + adh);

  // ---- phase A: max over all edges (chunks 0,1 cached in regs) ----
  int s0 = 0, s1 = 0;
  float e0 = NEGBIG, e1 = NEGBIG;
  if (rs + ep < re) {
    s0 = csr_src[rs + ep];
    e0 = lrelu(a_src[(size_t)s0 * 4 + h] + adh);
  }
  if (rs + 16 + ep < re) {
    s1 = csr_src[rs + 16 + ep];
    e1 = lrelu(a_src[(size_t)s1 * 4 + h] + adh);
  }
  float m = fmaxf(es, fmaxf(e0, e1));
  for (int base = rs + 32; base < re; base += 16) {   // rare (deg > 32)
    if (base + ep < re) {
      int s = csr_src[base + ep];
      m = fmaxf(m, lrelu(a_src[(size_t)s * 4 + h] + adh));
    }
  }
  #pragma unroll
  for (int off = 8; off > 0; off >>= 1) m = fmaxf(m, __shfl_xor(m, off));

  // ---- phase B: denominator (p0,p1 stay in regs) ----
  float p0 = expf(e0 - m), p1 = expf(e1 - m);         // 0 for invalid slots
  float dn = p0 + p1;
  for (int base = rs + 32; base < re; base += 16) {   // rare
    if (base + ep < re) {
      int s = csr_src[base + ep];
      dn += expf(lrelu(a_src[(size_t)s * 4 + h] + adh) - m);
    }
  }
  #pragma unroll
  for (int off = 8; off > 0; off >>= 1) dn += __shfl_xor(dn, off);
  float sp = expf(es - m);
  dn += sp;
  float rr = 1.f / (dn + EPSV);

  // ---- phase C: alpha records in LDS + dot2 aggregation ----
  unsigned short* recb = reinterpret_cast<unsigned short*>(&rec[w][0]);
  float acc = 0.f;
  const unsigned short* hl = ht16 + lane * 4;   // lane = channel in agg phase

  auto agg = [&](int cnt) {
    int k = 0;
    for (; k + 4 <= cnt; k += 4) {
      uint4 r0 = rec[w][k + 0], r1 = rec[w][k + 1];
      uint4 r2 = rec[w][k + 2], r3 = rec[w][k + 3];
      int t0 = __builtin_amdgcn_readfirstlane((int)r0.z);
      int t1 = __builtin_amdgcn_readfirstlane((int)r1.z);
      int t2 = __builtin_amdgcn_readfirstlane((int)r2.z);
      int t3 = __builtin_amdgcn_readfirstlane((int)r3.z);
      uint2 h0 = *reinterpret_cast<const uint2*>(hl + (size_t)t0 * HC);
      uint2 h1 = *reinterpret_cast<const uint2*>(hl + (size_t)t1 * HC);
      uint2 h2 = *reinterpret_cast<const uint2*>(hl + (size_t)t2 * HC);
      uint2 h3 = *reinterpret_cast<const uint2*>(hl + (size_t)t3 * HC);
      acc = dot2acc(r0.x, h0.x, acc); acc = dot2acc(r0.y, h0.y, acc);
      acc = dot2acc(r1.x, h1.x, acc); acc = dot2acc(r1.y, h1.y, acc);
      acc = dot2acc(r2.x, h2.x, acc); acc = dot2acc(r2.y, h2.y, acc);
      acc = dot2acc(r3.x, h3.x, acc); acc = dot2acc(r3.y, h3.y, acc);
    }
    for (; k < cnt; ++k) {
      uint4 r0 = rec[w][k];
      int t0 = __builtin_amdgcn_readfirstlane((int)r0.z);
      uint2 hv = *reinterpret_cast<const uint2*>(hl + (size_t)t0 * HC);
      acc = dot2acc(r0.x, hv.x, acc);
      acc = dot2acc(r0.y, hv.y, acc);
    }
  };

  // self record (slot 16) + chunk 0
  if (ep == 0) recb[16 * 8 + h] = f16b(sp * rr);
  recb[ep * 8 + h] = f16b(p0 * rr);
  if (h == 0) *reinterpret_cast<int*>(recb + ep * 8 + 4) = s0;
  {
    int cnt = re - rs; if (cnt > 16) cnt = 16;
    agg(cnt);
  }
  // chunk 1 (register-cached)
  if (re > rs + 16) {
    recb[ep * 8 + h] = f16b(p1 * rr);
    if (h == 0) *reinterpret_cast<int*>(recb + ep * 8 + 4) = s1;
    int cnt = re - rs - 16; if (cnt > 16) cnt = 16;
    agg(cnt);
  }
  // extra chunks (deg > 32, rare): recompute
  for (int base = rs + 32; base < re; base += 16) {
    int s = 0;
    float e = NEGBIG;
    if (base + ep < re) {
      s = csr_src[base + ep];
      e = lrelu(a_src[(size_t)s * 4 + h] + adh);
    }
    recb[ep * 8 + h] = f16b(expf(e - m) * rr);
    if (h == 0) *reinterpret_cast<int*>(recb + ep * 8 + 4) = s;
    int cnt = re - base; if (cnt > 16) cnt = 16;
    agg(cnt);
  }

  // ---- self message + finalize ----
  uint2 sa = *reinterpret_cast<const uint2*>(&rec[w][16]);   // uniform
  uint2 shv = *reinterpret_cast<const uint2*>(ht16 + (size_t)wid * HC + lane * 4);
  acc = dot2acc(sa.x, shv.x, acc);
  acc = dot2acc(sa.y, shv.y, acc);
  float v = acc * 0.25f + bias[lane];
  v = fmaxf(v, 0.f);
  if (do_lsm) {
    float mx = v;
    #pragma unroll
    for (int off = 32; off > 0; off >>= 1) mx = fmaxf(mx, __shfl_xor(mx, off));
    float ex = expf(v - mx);
    float sm = ex;
    #pragma unroll
    for (int off = 32; off > 0; off >>= 1) sm += __shfl_xor(sm, off);
    outf[(size_t)wid * CH + lane] = v - mx - logf(sm);
  } else {
    outb[(size_t)wid * CH + lane] = f2bf(v);
  }
}

extern "C" void kernel_launch(void* const* d_in, const int* in_sizes, int n_in,
                              void* d_out, int out_size, void* d_ws, size_t ws_size,
                              hipStream_t stream) {
  const float* x0 = (const float*)d_in[0];
  const int*   ei = (const int*)d_in[1];
  int N = in_sizes[0] / HC;   // 50000
  int E = in_sizes[1] / 2;    // 800000
  const int* srcp = ei;
  const int* dstp = ei + E;

  const float* W[3]  = {(const float*)d_in[2], (const float*)d_in[6],  (const float*)d_in[10]};
  const float* AS[3] = {(const float*)d_in[3], (const float*)d_in[7],  (const float*)d_in[11]};
  const float* AD[3] = {(const float*)d_in[4], (const float*)d_in[8],  (const float*)d_in[12]};
  const float* BI[3] = {(const float*)d_in[5], (const float*)d_in[9],  (const float*)d_in[13]};

  char* ws = (char*)d_ws;
  size_t off = 0;
  auto alloc = [&](size_t bytes) {
    void* p = ws + off;
    off += (bytes + 255) & ~(size_t)255;
    return p;
  };
  unsigned short* ht16    = (unsigned short*)alloc((size_t)N * HC * 2); // 25.6 MB (f16)
  unsigned short* xb16    = (unsigned short*)alloc((size_t)N * CH * 2); // 6.4 MB (bf16)
  float*          a_s     = (float*)alloc((size_t)N * 4 * 4);
  float*          a_d     = (float*)alloc((size_t)N * 4 * 4);
  int*            rowp    = (int*)alloc((size_t)(N + 1) * 4);
  int*            cursor  = (int*)alloc((size_t)N * 4);
  int*            csr_src = (int*)alloc((size_t)E * 4);                 // 3.2 MB
  int*            bsum    = (int*)alloc(512 * 4);
  unsigned short* Wt[3];
  Wt[0] = (unsigned short*)alloc((size_t)256 * 256 * 2);
  Wt[1] = (unsigned short*)alloc((size_t)256 * 64 * 2);
  Wt[2] = (unsigned short*)alloc((size_t)256 * 64 * 2);

  // ---- weight prep (bf16 transposed, all layers, one launch) ----
  wprep3_k<<<384, 256, 0, stream>>>(W[0], W[1], W[2], Wt[0], Wt[1], Wt[2]);

  // ---- build CSR by destination (once; reused by all 3 layers) ----
  int nb = (N + 511) / 512;
  hipMemsetAsync(cursor, 0, (size_t)N * 4, stream);
  hipMemsetAsync(rowp, 0, (size_t)N * 4, stream);
  hist_k<<<(E + 255) / 256, 256, 0, stream>>>(dstp, rowp, E);
  scan1_k<<<nb, 512, 0, stream>>>(rowp, rowp, bsum, N);
  scan2_k<<<1, 128, 0, stream>>>(bsum, nb);
  scan3_k<<<nb, 512, 0, stream>>>(rowp, bsum, N, E);
  scatter_k<<<(E + 255) / 256, 256, 0, stream>>>(srcp, dstp, rowp, cursor, csr_src, E);

  int gblocks = (N + 31) / 32;
  for (int L = 0; L < 3; ++L) {
    if (L == 0)
      mfma_gat_k<256, 1><<<gblocks, 256, 0, stream>>>(x0, nullptr, Wt[0], AS[0], AD[0],
                                                      ht16, a_s, a_d, N);
    else
      mfma_gat_k<64, 0><<<gblocks, 256, 0, stream>>>(nullptr, xb16, Wt[L], AS[L], AD[L],
                                                     ht16, a_s, a_d, N);
    soft_agg_k<<<(N + 3) / 4, 256, 0, stream>>>(rowp, csr_src, a_s, a_d, ht16, BI[L],
                                                (float*)d_out, xb16, N, (L == 2) ? 1 : 0);
  }
}